// Round 4
// baseline (139.411 us; speedup 1.0000x reference)
//
#include <hip/hip_runtime.h>
#include <hip/hip_bf16.h>
#include <math.h>

// Problem constants
#define Bdim 2
#define Tdim 512
#define Cdim 256
#define Hdim 8
#define Edim 32
#define NTYPES 16
#define TI 8       // i-tile size
#define JT 128     // j-tile size

// ---------------------------------------------------------------------------
// Kernel 1: fused edge-tables + qkv GEMM.
// blocks 0..383: qkv GEMM (M=1024,K=256,N=768), 32x64 tile, scatter (B,H,T,E)
// blocks 384..399: ekt/evt = emb[t] @ w_edge_{k,v}
// ---------------------------------------------------------------------------
__global__ __launch_bounds__(256) void pre_kernel(
    const float* __restrict__ A, const float* __restrict__ Bw,
    const float* __restrict__ emb, const float* __restrict__ wk,
    const float* __restrict__ wv,
    float* __restrict__ qT, float* __restrict__ kT, float* __restrict__ vT,
    float* __restrict__ ekt, float* __restrict__ evt)
{
    __shared__ float smem[16 * 34 + 16 * 64];
    int tid = threadIdx.x;

    if (blockIdx.x >= 384) {
        // ---- edge tables ----
        int t = blockIdx.x - 384;
        float* se = smem;
        se[tid] = emb[t * Cdim + tid];
        __syncthreads();
        float a = 0.f, b = 0.f;
        for (int k = 0; k < Cdim; ++k) {
            float ev = se[k];
            a = fmaf(ev, wk[k * Cdim + tid], a);
            b = fmaf(ev, wv[k * Cdim + tid], b);
        }
        ekt[t * Cdim + tid] = a;
        evt[t * Cdim + tid] = b;
        return;
    }

    const int N = 3 * Cdim;
    const int K = Cdim;
    float (*As)[34] = (float(*)[34])smem;
    float (*Bs)[64] = (float(*)[64])(smem + 16 * 34);
    int m0 = (blockIdx.x / 12) * 32;
    int n0 = (blockIdx.x % 12) * 64;
    int tr = tid >> 4, tc = tid & 15;
    float acc[2][4] = {};
    int bkr = tid >> 4, bcq = (tid & 15) * 4;

    for (int k0 = 0; k0 < K; k0 += 16) {
        if (tid < 128) {
            int r = tid >> 2, kq = (tid & 3) * 4;
            float4 av = *(const float4*)(A + (size_t)(m0 + r) * K + k0 + kq);
            As[kq + 0][r] = av.x;
            As[kq + 1][r] = av.y;
            As[kq + 2][r] = av.z;
            As[kq + 3][r] = av.w;
        }
        float4 bv = *(const float4*)(Bw + (size_t)(k0 + bkr) * N + n0 + bcq);
        *(float4*)&Bs[bkr][bcq] = bv;
        __syncthreads();
#pragma unroll
        for (int kk = 0; kk < 16; ++kk) {
            float2 a2 = *(float2*)&As[kk][tr * 2];
            float4 b4 = *(float4*)&Bs[kk][tc * 4];
            acc[0][0] = fmaf(a2.x, b4.x, acc[0][0]);
            acc[0][1] = fmaf(a2.x, b4.y, acc[0][1]);
            acc[0][2] = fmaf(a2.x, b4.z, acc[0][2]);
            acc[0][3] = fmaf(a2.x, b4.w, acc[0][3]);
            acc[1][0] = fmaf(a2.y, b4.x, acc[1][0]);
            acc[1][1] = fmaf(a2.y, b4.y, acc[1][1]);
            acc[1][2] = fmaf(a2.y, b4.z, acc[1][2]);
            acc[1][3] = fmaf(a2.y, b4.w, acc[1][3]);
        }
        __syncthreads();
    }
    int sec = n0 >> 8;
    float* dst = (sec == 0) ? qT : (sec == 1) ? kT : vT;
    int cc0 = (n0 & 255) + tc * 4;
    int h = cc0 >> 5;
    int e0 = cc0 & 31;
#pragma unroll
    for (int i = 0; i < 2; ++i) {
        int m = m0 + tr * 2 + i;
        int bq = m >> 9, t = m & (Tdim - 1);
        float4 val = make_float4(acc[i][0], acc[i][1], acc[i][2], acc[i][3]);
        *(float4*)&dst[(((size_t)bq * Hdim + h) * Tdim + t) * Edim + e0] = val;
    }
}

// ---------------------------------------------------------------------------
// Kernel 2: attention. Round-14: NO kv LDS STAGING — k/v read directly from
// global (k/v tiles are 16KB, L1-resident within a block; kT/vT=1MB total,
// L2-resident). R13 analysis: LDS pipe was the busiest resource (~600cy/wave
// per tile-pair of ds_read_b128) and ~13 barriers/block drained it each time;
// staging cache-fit data through LDS was pure overhead (guide §5 mistake 7).
// Now: pass A/B are barrier-FREE loops (global k4/v4 loads overlap across
// iterations and waves); 5 barriers/block total. LDS 36.4KB = qm(16K,
// XOR-swz) + ss(16K) + st1pf(2K) + sevt(2.25K) + sabt/sinv -> 3-4 blocks/CU
// at natural VGPR (~64-80), grid 1024 (1 rep/block, LPT heavy-first).
// WATCH: VGPR <= 84 keeps 3 blocks/CU; <= 64 gives 4.
// Do NOT: min-waves>4 in __launch_bounds__ (R12: 40-VGPR forced spill, 161MB
// scratch traffic), kv dbuf (R11: 0 gain), online softmax (R7-R9), qm removal
// (R10: +3us VALU), LDS-staging of k/v (R13: pipe+barrier cost > reuse win).
// ---------------------------------------------------------------------------
__global__ __launch_bounds__(512, 4) void attn_kernel(
    const float* __restrict__ qT, const float* __restrict__ kT,
    const float* __restrict__ vT, const int* __restrict__ bm,
    const float* __restrict__ ekt, const float* __restrict__ evt,
    const float* __restrict__ abt, float* __restrict__ y)
{
    __shared__ float qm[TI][NTYPES][32];         // q*ekt, XOR-swizzled (16K)
    __shared__ float ss[TI][512];                // scores -> probs (16K)
    __shared__ unsigned int st1pf[Tdim];         // nibbles of bm[b,j,i0+ii] (2K)
    __shared__ float sevt[NTYPES][36];           // (2.25K)
    __shared__ float sabt[NTYPES];
    __shared__ float sinv[TI];
    // total ~36.4 KB

    float* spart = (float*)ss;                   // overlay AFTER pass B done

    // global LPT order: heaviest tau (njt=4) blocks dispatch first
    const int tau = 63 - (blockIdx.x >> 4);
    const int bh = blockIdx.x & 15;
    const int h = bh & (Hdim - 1);
    const int b = bh >> 3;
    const int tid = threadIdx.x;
    const int wave = tid >> 6;
    const int lane = tid & 63;
    const float inv_scale = 0.17677669529663687f;  // 1/sqrt(32)

    const float* qbase = qT + (size_t)bh * Tdim * Edim;
    const float* kbase = kT + (size_t)bh * Tdim * Edim;
    const float* vbase = vT + (size_t)bh * Tdim * Edim;
    const int* bmb = bm + (size_t)b * Tdim * Tdim;

    const int i0 = tau * TI;
    const int imax = i0 + TI - 1;
    const int njt = (imax >> 7) + 1;
    const int jmax = njt << 7;

    if (tid < 128) {
        int t = tid >> 3, eq = tid & 7;
        *(float4*)&sevt[t][eq * 4] = *(const float4*)&evt[t * Cdim + h * Edim + eq * 4];
    }
    if (tid < NTYPES) sabt[tid] = abt[tid * Hdim + h];
    // stage nibble table st1pf[j]: bm[b, j, i0..i0+7]
    if (tid < jmax) {
        const int* rowp = bmb + (size_t)tid * Tdim + i0;
        int4 lo = *(const int4*)rowp;
        int4 hi = *(const int4*)(rowp + 4);
        st1pf[tid] =
            ((unsigned)(lo.x & 15)) | (((unsigned)(lo.y & 15)) << 4) |
            (((unsigned)(lo.z & 15)) << 8) | (((unsigned)(lo.w & 15)) << 12) |
            (((unsigned)(hi.x & 15)) << 16) | (((unsigned)(hi.y & 15)) << 20) |
            (((unsigned)(hi.z & 15)) << 24) | (((unsigned)(hi.w & 15)) << 28);
    }
    // build qm[ii][t] = q[i0+ii] * ekt[t] directly from global (L1 absorbs
    // the x16 q-row and x8 ekt-row redundancy)
    for (int idx = tid; idx < TI * NTYPES * 8; idx += 512) {
        int eq = idx & 7;
        int t = (idx >> 3) & (NTYPES - 1);
        int r = idx >> 7;
        float4 qv = *(const float4*)&qbase[(size_t)(i0 + r) * Edim + eq * 4];
        float4 ev = *(const float4*)&ekt[t * Cdim + h * Edim + eq * 4];
        float4 o;
        o.x = qv.x * ev.x; o.y = qv.y * ev.y;
        o.z = qv.z * ev.z; o.w = qv.w * ev.w;
        *(float4*)&qm[r][t][(eq << 2) ^ ((t & 7) << 2)] = o;
    }
    __syncthreads();   // [bar 1] qm + st1pf + sevt + sabt ready

    // -------- Pass A: scores. NO BARRIERS; k straight from global/L1 --------
    {
        const int jsub = wave & 1;
        const int ii0 = wave >> 1;
        const int jl = (jsub << 6) + lane;
        for (int jt = 0; jt < njt; ++jt) {
            int j0 = jt << 7;
            if (j0 + (jsub << 6) > imax) break;   // wave-uniform; j0 only grows
            int j = j0 + jl;
            unsigned tp = st1pf[j];               // issued alongside k loads
            const float* krow = kbase + ((size_t)j << 5);
            float4 k4[8];
#pragma unroll
            for (int eq = 0; eq < 8; ++eq)
                k4[eq] = *(const float4*)(krow + eq * 4);

#pragma unroll
            for (int u = 0; u < 2; ++u) {
                int ii = ii0 + (u << 2);
                int i = i0 + ii;
                if (j0 + (jsub << 6) > i) continue;   // wave-uniform skip
                int t1 = (tp >> (ii * 4)) & 15;
                const int qsw = (t1 & 7) << 2;
                float s0 = 0.f, s1 = 0.f;
#pragma unroll
                for (int eq = 0; eq < 8; ++eq) {
                    float4 qv = *(float4*)&qm[ii][t1][(eq << 2) ^ qsw];
                    s0 = fmaf(qv.x, k4[eq].x, s0);
                    s1 = fmaf(qv.y, k4[eq].y, s1);
                    s0 = fmaf(qv.z, k4[eq].z, s0);
                    s1 = fmaf(qv.w, k4[eq].w, s1);
                }
                if (j <= i) ss[ii][j] = (s0 + s1) * inv_scale;
            }
        }
    }
    __syncthreads();   // [bar 2] all scores written

    // ------- softmax (bias added here from global bm; norm deferred) -------
    {
        int ii = wave;
        int i = i0 + ii;
        const int* brow = bmb + (size_t)i * Tdim;   // bm[b, i, :], coalesced
        float tb[8];
        float m = -1e30f;
#pragma unroll
        for (int c = 0; c < 8; ++c) {
            int j = (c << 6) + lane;                // always < Tdim: safe read
            float val = ss[ii][j] + sabt[brow[j] & 15];
            tb[c] = (j <= i) ? val : -1e30f;        // select AFTER add: no NaN
            m = fmaxf(m, tb[c]);
        }
        for (int off = 32; off; off >>= 1) m = fmaxf(m, __shfl_xor(m, off));
        float sum = 0.f;
#pragma unroll
        for (int c = 0; c < 8; ++c) {
            int j = (c << 6) + lane;
            float p = __expf(tb[c] - m);
            p = (j <= i) ? p : 0.f;                 // kill exp(0)=1 of idle lanes
            sum += p;
            if (j <= i) ss[ii][j] = p;
        }
        for (int off = 32; off; off >>= 1) sum += __shfl_xor(sum, off);
        if (lane == 0) sinv[ii] = 1.0f / sum;
    }
    __syncthreads();   // [bar 3] probs + sinv visible

    // -------- Pass B: PV. NO BARRIERS; v straight from global/L1 ------------
    float4 acc[TI];
#pragma unroll
    for (int ii = 0; ii < TI; ++ii) acc[ii] = make_float4(0.f, 0.f, 0.f, 0.f);
    {
        const int gid = tid >> 3;        // 64 groups of 8 (8 lanes share a j)
        const int eqg4 = (tid & 7) << 2;
        for (int jt = 0; jt < njt; ++jt) {
            int j0 = jt << 7;
#pragma unroll
            for (int sub = 0; sub < 2; ++sub) {
                if (j0 + (sub << 6) > imax) continue;  // block-uniform skip
                int jl = (sub << 6) + gid;
                int j = j0 + jl;
                float4 v4 = *(const float4*)&vbase[((size_t)j << 5) + eqg4];
                unsigned tp = st1pf[j];
#pragma unroll
                for (int ii = 0; ii < TI; ++ii) {
                    int i = i0 + ii;
                    if (j0 + (sub << 6) > i) continue;  // block-uniform skip
                    float p = (j <= i) ? ss[ii][j] : 0.f;
                    int t1 = (tp >> (ii * 4)) & 15;
                    float4 ev = *(float4*)&sevt[t1][eqg4];
                    acc[ii].x = fmaf(p * ev.x, v4.x, acc[ii].x);
                    acc[ii].y = fmaf(p * ev.y, v4.y, acc[ii].y);
                    acc[ii].z = fmaf(p * ev.z, v4.z, acc[ii].z);
                    acc[ii].w = fmaf(p * ev.w, v4.w, acc[ii].w);
                }
            }
        }
    }
    __syncthreads();   // [bar 4] all ss reads done -> spart may overlay
    // reduce across the wave's 8 groups (lane bits 3,4,5)
#pragma unroll
    for (int ii = 0; ii < TI; ++ii) {
#pragma unroll
        for (int m = 8; m <= 32; m <<= 1) {
            acc[ii].x += __shfl_xor(acc[ii].x, m);
            acc[ii].y += __shfl_xor(acc[ii].y, m);
            acc[ii].z += __shfl_xor(acc[ii].z, m);
            acc[ii].w += __shfl_xor(acc[ii].w, m);
        }
    }
    if (lane < 8) {
#pragma unroll
        for (int ii = 0; ii < TI; ++ii)
            *(float4*)&spart[((wave * TI + ii) << 5) + lane * 4] = acc[ii];
    }
    __syncthreads();   // [bar 5]
    if (tid < TI * Edim) {
        int ii = tid >> 5, e = tid & 31;
        float yv = 0.f;
#pragma unroll
        for (int w = 0; w < 8; ++w) yv += spart[((w * TI + ii) << 5) + e];
        yv *= sinv[ii];
        y[((size_t)(b * Tdim + i0 + ii)) * Cdim + h * Edim + e] = yv;
    }
}

// ---------------------------------------------------------------------------
// Kernel 3: proj GEMM (M=1024, K=256, N=256) -> d_out (B,T,C), 32x64 tiles
// ---------------------------------------------------------------------------
__global__ __launch_bounds__(256) void proj_gemm_kernel(
    const float* __restrict__ A, const float* __restrict__ Bw,
    float* __restrict__ out)
{
    const int N = Cdim;
    const int K = Cdim;
    __shared__ float As[16][34];
    __shared__ float Bs[16][64];
    int m0 = blockIdx.y * 32;
    int n0 = blockIdx.x * 64;
    int tid = threadIdx.x;
    int tr = tid >> 4, tc = tid & 15;
    float acc[2][4] = {};
    int bkr = tid >> 4, bcq = (tid & 15) * 4;

    for (int k0 = 0; k0 < K; k0 += 16) {
        if (tid < 128) {
            int r = tid >> 2, kq = (tid & 3) * 4;
            float4 av = *(const float4*)(A + (size_t)(m0 + r) * K + k0 + kq);
            As[kq + 0][r] = av.x;
            As[kq + 1][r] = av.y;
            As[kq + 2][r] = av.z;
            As[kq + 3][r] = av.w;
        }
        float4 bv = *(const float4*)(Bw + (size_t)(k0 + bkr) * N + n0 + bcq);
        *(float4*)&Bs[bkr][bcq] = bv;
        __syncthreads();
#pragma unroll
        for (int kk = 0; kk < 16; ++kk) {
            float2 a2 = *(float2*)&As[kk][tr * 2];
            float4 b4 = *(float4*)&Bs[kk][tc * 4];
            acc[0][0] = fmaf(a2.x, b4.x, acc[0][0]);
            acc[0][1] = fmaf(a2.x, b4.y, acc[0][1]);
            acc[0][2] = fmaf(a2.x, b4.z, acc[0][2]);
            acc[0][3] = fmaf(a2.x, b4.w, acc[0][3]);
            acc[1][0] = fmaf(a2.y, b4.x, acc[1][0]);
            acc[1][1] = fmaf(a2.y, b4.y, acc[1][1]);
            acc[1][2] = fmaf(a2.y, b4.z, acc[1][2]);
            acc[1][3] = fmaf(a2.y, b4.w, acc[1][3]);
        }
        __syncthreads();
    }
#pragma unroll
    for (int i = 0; i < 2; ++i) {
        int m = m0 + tr * 2 + i;
        float4 val = make_float4(acc[i][0], acc[i][1], acc[i][2], acc[i][3]);
        *(float4*)&out[(size_t)m * N + n0 + tc * 4] = val;
    }
}

// ---------------------------------------------------------------------------
extern "C" void kernel_launch(void* const* d_in, const int* in_sizes, int n_in,
                              void* d_out, int out_size, void* d_ws, size_t ws_size,
                              hipStream_t stream) {
    (void)in_sizes; (void)n_in; (void)out_size; (void)ws_size;
    const float* x = (const float*)d_in[0];
    const int* bias_matrix = (const int*)d_in[1];
    const float* w_attn = (const float*)d_in[2];
    const float* w_proj = (const float*)d_in[3];
    const float* w_edge_k = (const float*)d_in[4];
    const float* w_edge_v = (const float*)d_in[5];
    const float* edge_emb = (const float*)d_in[6];
    const float* attn_bias = (const float*)d_in[7];
    float* out = (float*)d_out;

    const size_t n_qkv = (size_t)Bdim * Hdim * Tdim * Edim;
    float* ws = (float*)d_ws;
    float* qT = ws;
    float* kT = qT + n_qkv;
    float* vT = kT + n_qkv;
    float* y = vT + n_qkv;
    float* ekt = y + (size_t)Bdim * Tdim * Cdim;
    float* evt = ekt + (size_t)NTYPES * Cdim;

    pre_kernel<<<400, 256, 0, stream>>>(x, w_attn, edge_emb, w_edge_k, w_edge_v,
                                        qT, kT, vT, ekt, evt);
    attn_kernel<<<dim3(64 * 16), 512, 0, stream>>>(qT, kT, vT, bias_matrix,
                                                   ekt, evt, attn_bias, y);
    proj_gemm_kernel<<<dim3(4, 32), 256, 0, stream>>>(y, w_proj, out);
}

// Round 5
// 129.037 us; speedup vs baseline: 1.0804x; 1.0804x over previous
//
#include <hip/hip_runtime.h>
#include <hip/hip_bf16.h>
#include <math.h>

// Problem constants
#define Bdim 2
#define Tdim 512
#define Cdim 256
#define Hdim 8
#define Edim 32
#define NTYPES 16
#define TI 8       // i-tile size

// ---------------------------------------------------------------------------
// Kernel 1: fused edge-tables + qkv GEMM.
// blocks 0..383: qkv GEMM (M=1024,K=256,N=768), 32x64 tile, scatter (B,H,T,E)
// blocks 384..399: ekt/evt = emb[t] @ w_edge_{k,v}
// ---------------------------------------------------------------------------
__global__ __launch_bounds__(256) void pre_kernel(
    const float* __restrict__ A, const float* __restrict__ Bw,
    const float* __restrict__ emb, const float* __restrict__ wk,
    const float* __restrict__ wv,
    float* __restrict__ qT, float* __restrict__ kT, float* __restrict__ vT,
    float* __restrict__ ekt, float* __restrict__ evt)
{
    __shared__ float smem[16 * 34 + 16 * 64];
    int tid = threadIdx.x;

    if (blockIdx.x >= 384) {
        // ---- edge tables ----
        int t = blockIdx.x - 384;
        float* se = smem;
        se[tid] = emb[t * Cdim + tid];
        __syncthreads();
        float a = 0.f, b = 0.f;
        for (int k = 0; k < Cdim; ++k) {
            float ev = se[k];
            a = fmaf(ev, wk[k * Cdim + tid], a);
            b = fmaf(ev, wv[k * Cdim + tid], b);
        }
        ekt[t * Cdim + tid] = a;
        evt[t * Cdim + tid] = b;
        return;
    }

    const int N = 3 * Cdim;
    const int K = Cdim;
    float (*As)[34] = (float(*)[34])smem;
    float (*Bs)[64] = (float(*)[64])(smem + 16 * 34);
    int m0 = (blockIdx.x / 12) * 32;
    int n0 = (blockIdx.x % 12) * 64;
    int tr = tid >> 4, tc = tid & 15;
    float acc[2][4] = {};
    int bkr = tid >> 4, bcq = (tid & 15) * 4;

    for (int k0 = 0; k0 < K; k0 += 16) {
        if (tid < 128) {
            int r = tid >> 2, kq = (tid & 3) * 4;
            float4 av = *(const float4*)(A + (size_t)(m0 + r) * K + k0 + kq);
            As[kq + 0][r] = av.x;
            As[kq + 1][r] = av.y;
            As[kq + 2][r] = av.z;
            As[kq + 3][r] = av.w;
        }
        float4 bv = *(const float4*)(Bw + (size_t)(k0 + bkr) * N + n0 + bcq);
        *(float4*)&Bs[bkr][bcq] = bv;
        __syncthreads();
#pragma unroll
        for (int kk = 0; kk < 16; ++kk) {
            float2 a2 = *(float2*)&As[kk][tr * 2];
            float4 b4 = *(float4*)&Bs[kk][tc * 4];
            acc[0][0] = fmaf(a2.x, b4.x, acc[0][0]);
            acc[0][1] = fmaf(a2.x, b4.y, acc[0][1]);
            acc[0][2] = fmaf(a2.x, b4.z, acc[0][2]);
            acc[0][3] = fmaf(a2.x, b4.w, acc[0][3]);
            acc[1][0] = fmaf(a2.y, b4.x, acc[1][0]);
            acc[1][1] = fmaf(a2.y, b4.y, acc[1][1]);
            acc[1][2] = fmaf(a2.y, b4.z, acc[1][2]);
            acc[1][3] = fmaf(a2.y, b4.w, acc[1][3]);
        }
        __syncthreads();
    }
    int sec = n0 >> 8;
    float* dst = (sec == 0) ? qT : (sec == 1) ? kT : vT;
    int cc0 = (n0 & 255) + tc * 4;
    int h = cc0 >> 5;
    int e0 = cc0 & 31;
#pragma unroll
    for (int i = 0; i < 2; ++i) {
        int m = m0 + tr * 2 + i;
        int bq = m >> 9, t = m & (Tdim - 1);
        float4 val = make_float4(acc[i][0], acc[i][1], acc[i][2], acc[i][3]);
        *(float4*)&dst[(((size_t)bq * Hdim + h) * Tdim + t) * Edim + e0] = val;
    }
}

// Quad (4-lane) butterfly sum via DPP quad_perm — pure VALU, no LDS pipe.
__device__ __forceinline__ float quad_reduce_add(float s) {
    int t = __builtin_amdgcn_update_dpp(0, __float_as_int(s), 0xB1, 0xF, 0xF, true); // xor1
    s += __int_as_float(t);
    t = __builtin_amdgcn_update_dpp(0, __float_as_int(s), 0x4E, 0xF, 0xF, true);     // xor2
    s += __int_as_float(t);
    return s;
}

// ---------------------------------------------------------------------------
// Kernel 2: attention. Round-15: COALESCED GLOBAL-DIRECT pass A.
// R14 post-mortem: dropping kv LDS staging was right for pass B (v loads were
// group-coalesced: 8 lanes/row = 1KB/wave, fine) but pass A's per-lane k-row
// scatter (64 rows per instr) serialized the VMEM pipe -> 46us. LDS staging
// was only ever a COALESCING device; replace it with coalesced geometry:
// pass A now uses 4 lanes per j (lane c owns an 8-elem e-slice): wave k-read
// = 16 consecutive rows x 32B/lane = 2KB contiguous (2 dwordx4). Partial dots
// reduce with quad_perm DPP adds (zero LDS). Per-ii result selected onto lane
// c==ii&3 via compile-time cndmasks (no runtime-indexed array -> no scratch).
// LDS/128-pairs: 26 b128 (R13) -> 16 b128 + 3 b32; no pass-A barriers; kv
// buffer deleted (37.5KB total -> 4 blocks/CU if VGPR<=64). 5 barriers/block.
// Do NOT: min-waves>4 (R12: forced spill), per-lane-row global k (R14:
// scatter serialization), kv dbuf (R11: 0 gain), online softmax (R7-R9),
// qm removal (R10: +3us VALU).
// ---------------------------------------------------------------------------
__global__ __launch_bounds__(512, 4) void attn_kernel(
    const float* __restrict__ qT, const float* __restrict__ kT,
    const float* __restrict__ vT, const int* __restrict__ bm,
    const float* __restrict__ ekt, const float* __restrict__ evt,
    const float* __restrict__ abt, float* __restrict__ y)
{
    __shared__ float qm[TI][NTYPES][32];         // q*ekt, XOR-swizzled (16K)
    __shared__ float ss[TI][516];                // scores -> probs (16.1K)
    __shared__ unsigned int st1pf[Tdim];         // nibbles of bm[b,j,i0+ii] (2K)
    __shared__ float sevt[NTYPES][36];           // (2.25K)
    __shared__ float sabt[NTYPES];
    __shared__ float sinv[TI];
    // total ~36.6 KB

    float* spart = (float*)ss;                   // overlay AFTER pass B done

    // global LPT order: heaviest tau (njt=4) blocks dispatch first
    const int tau = 63 - (blockIdx.x >> 4);
    const int bh = blockIdx.x & 15;
    const int h = bh & (Hdim - 1);
    const int b = bh >> 3;
    const int tid = threadIdx.x;
    const int wave = tid >> 6;
    const int lane = tid & 63;
    const float inv_scale = 0.17677669529663687f;  // 1/sqrt(32)

    const float* qbase = qT + (size_t)bh * Tdim * Edim;
    const float* kbase = kT + (size_t)bh * Tdim * Edim;
    const float* vbase = vT + (size_t)bh * Tdim * Edim;
    const int* bmb = bm + (size_t)b * Tdim * Tdim;

    const int i0 = tau * TI;
    const int imax = i0 + TI - 1;
    const int jmax = (((imax >> 7) + 1) << 7);

    if (tid < 128) {
        int t = tid >> 3, eq = tid & 7;
        *(float4*)&sevt[t][eq * 4] = *(const float4*)&evt[t * Cdim + h * Edim + eq * 4];
    }
    if (tid < NTYPES) sabt[tid] = abt[tid * Hdim + h];
    // stage nibble table st1pf[j]: bm[b, j, i0..i0+7]
    if (tid < jmax) {
        const int* rowp = bmb + (size_t)tid * Tdim + i0;
        int4 lo = *(const int4*)rowp;
        int4 hi = *(const int4*)(rowp + 4);
        st1pf[tid] =
            ((unsigned)(lo.x & 15)) | (((unsigned)(lo.y & 15)) << 4) |
            (((unsigned)(lo.z & 15)) << 8) | (((unsigned)(lo.w & 15)) << 12) |
            (((unsigned)(hi.x & 15)) << 16) | (((unsigned)(hi.y & 15)) << 20) |
            (((unsigned)(hi.z & 15)) << 24) | (((unsigned)(hi.w & 15)) << 28);
    }
    // build qm[ii][t] = q[i0+ii] * ekt[t] directly from global (L1 absorbs
    // the x16 q-row and x8 ekt-row redundancy); quad-XOR swizzle on (t&7)
    for (int idx = tid; idx < TI * NTYPES * 8; idx += 512) {
        int eq = idx & 7;
        int t = (idx >> 3) & (NTYPES - 1);
        int r = idx >> 7;
        float4 qv = *(const float4*)&qbase[(size_t)(i0 + r) * Edim + eq * 4];
        float4 ev = *(const float4*)&ekt[t * Cdim + h * Edim + eq * 4];
        float4 o;
        o.x = qv.x * ev.x; o.y = qv.y * ev.y;
        o.z = qv.z * ev.z; o.w = qv.w * ev.w;
        *(float4*)&qm[r][t][(eq << 2) ^ ((t & 7) << 2)] = o;
    }
    __syncthreads();   // [bar 1] qm + st1pf + sevt + sabt ready

    // ---- Pass A: scores. Coalesced global k (2KB/wave), DPP quad reduce ----
    {
        const int g = lane >> 2;     // j sub-index within wave's 16-row strip
        const int c = lane & 3;      // e-slice: elements c*8 .. c*8+7
        const int e0 = c << 3;
        for (int jb = wave << 4; jb <= imax; jb += 128) {
            const int j = jb + g;
            const float* krow = kbase + ((size_t)j << 5) + e0;
            float4 k0 = *(const float4*)(krow);
            float4 k1 = *(const float4*)(krow + 4);
            unsigned tp = st1pf[j];
            float my0 = 0.f, my1 = 0.f;
#pragma unroll
            for (int ii = 0; ii < 8; ++ii) {
                int t1 = (tp >> (ii * 4)) & 15;
                int o0 = e0 ^ ((t1 & 7) << 2);
                float4 q0 = *(float4*)&qm[ii][t1][o0];
                float4 q1 = *(float4*)&qm[ii][t1][o0 ^ 4];
                float s = q0.x * k0.x;
                s = fmaf(q0.y, k0.y, s);
                s = fmaf(q0.z, k0.z, s);
                s = fmaf(q0.w, k0.w, s);
                s = fmaf(q1.x, k1.x, s);
                s = fmaf(q1.y, k1.y, s);
                s = fmaf(q1.z, k1.z, s);
                s = fmaf(q1.w, k1.w, s);
                s = quad_reduce_add(s);          // all 4 lanes hold full dot
                if (ii < 4) my0 = (c == ii) ? s : my0;       // static select
                else        my1 = (c == (ii - 4)) ? s : my1;
            }
            if (j <= i0 + c)     ss[c][j]     = my0 * inv_scale;
            if (j <= i0 + c + 4) ss[c + 4][j] = my1 * inv_scale;
        }
    }
    __syncthreads();   // [bar 2] all scores written

    // ------- softmax (bias added here from global bm; norm deferred) -------
    {
        int ii = wave;
        int i = i0 + ii;
        const int* brow = bmb + (size_t)i * Tdim;   // bm[b, i, :], coalesced
        float tb[8];
        float m = -1e30f;
#pragma unroll
        for (int c = 0; c < 8; ++c) {
            int j = (c << 6) + lane;                // always < Tdim: safe read
            float val = ss[ii][j] + sabt[brow[j] & 15];
            tb[c] = (j <= i) ? val : -1e30f;        // select AFTER add: no NaN
            m = fmaxf(m, tb[c]);
        }
        for (int off = 32; off; off >>= 1) m = fmaxf(m, __shfl_xor(m, off));
        float sum = 0.f;
#pragma unroll
        for (int c = 0; c < 8; ++c) {
            int j = (c << 6) + lane;
            float p = __expf(tb[c] - m);
            p = (j <= i) ? p : 0.f;                 // kill exp(0)=1 of idle lanes
            sum += p;
            if (j <= i) ss[ii][j] = p;
        }
        for (int off = 32; off; off >>= 1) sum += __shfl_xor(sum, off);
        if (lane == 0) sinv[ii] = 1.0f / sum;
    }
    __syncthreads();   // [bar 3] probs + sinv visible

    // ---- Pass B: PV. Global-direct v (group-coalesced, R14-proven OK) ------
    float4 acc[TI];
#pragma unroll
    for (int ii = 0; ii < TI; ++ii) acc[ii] = make_float4(0.f, 0.f, 0.f, 0.f);
    {
        const int gid8 = tid >> 3;       // 64 groups of 8 (8 lanes share a j)
        const int eqg4 = (tid & 7) << 2;
        for (int jc = 0; (jc << 6) <= imax; ++jc) {
            const int j = (jc << 6) + gid8;
            float4 v4 = *(const float4*)&vbase[((size_t)j << 5) + eqg4];
            unsigned tp = st1pf[j];
#pragma unroll
            for (int ii = 0; ii < TI; ++ii) {
                const int i = i0 + ii;
                if ((jc << 6) > i) continue;        // block-uniform skip
                float p = (j <= i) ? ss[ii][j] : 0.f;
                int t1 = (tp >> (ii * 4)) & 15;
                float4 ev = *(float4*)&sevt[t1][eqg4];
                acc[ii].x = fmaf(p * ev.x, v4.x, acc[ii].x);
                acc[ii].y = fmaf(p * ev.y, v4.y, acc[ii].y);
                acc[ii].z = fmaf(p * ev.z, v4.z, acc[ii].z);
                acc[ii].w = fmaf(p * ev.w, v4.w, acc[ii].w);
            }
        }
    }
    __syncthreads();   // [bar 4] all ss reads done -> spart may overlay
    // reduce across the wave's 8 groups (lane bits 3,4,5)
#pragma unroll
    for (int ii = 0; ii < TI; ++ii) {
#pragma unroll
        for (int m = 8; m <= 32; m <<= 1) {
            acc[ii].x += __shfl_xor(acc[ii].x, m);
            acc[ii].y += __shfl_xor(acc[ii].y, m);
            acc[ii].z += __shfl_xor(acc[ii].z, m);
            acc[ii].w += __shfl_xor(acc[ii].w, m);
        }
    }
    if (lane < 8) {
#pragma unroll
        for (int ii = 0; ii < TI; ++ii)
            *(float4*)&spart[((wave * TI + ii) << 5) + lane * 4] = acc[ii];
    }
    __syncthreads();   // [bar 5]
    if (tid < TI * Edim) {
        int ii = tid >> 5, e = tid & 31;
        float yv = 0.f;
#pragma unroll
        for (int w = 0; w < 8; ++w) yv += spart[((w * TI + ii) << 5) + e];
        yv *= sinv[ii];
        y[((size_t)(b * Tdim + i0 + ii)) * Cdim + h * Edim + e] = yv;
    }
}

// ---------------------------------------------------------------------------
// Kernel 3: proj GEMM (M=1024, K=256, N=256) -> d_out (B,T,C), 32x64 tiles
// ---------------------------------------------------------------------------
__global__ __launch_bounds__(256) void proj_gemm_kernel(
    const float* __restrict__ A, const float* __restrict__ Bw,
    float* __restrict__ out)
{
    const int N = Cdim;
    const int K = Cdim;
    __shared__ float As[16][34];
    __shared__ float Bs[16][64];
    int m0 = blockIdx.y * 32;
    int n0 = blockIdx.x * 64;
    int tid = threadIdx.x;
    int tr = tid >> 4, tc = tid & 15;
    float acc[2][4] = {};
    int bkr = tid >> 4, bcq = (tid & 15) * 4;

    for (int k0 = 0; k0 < K; k0 += 16) {
        if (tid < 128) {
            int r = tid >> 2, kq = (tid & 3) * 4;
            float4 av = *(const float4*)(A + (size_t)(m0 + r) * K + k0 + kq);
            As[kq + 0][r] = av.x;
            As[kq + 1][r] = av.y;
            As[kq + 2][r] = av.z;
            As[kq + 3][r] = av.w;
        }
        float4 bv = *(const float4*)(Bw + (size_t)(k0 + bkr) * N + n0 + bcq);
        *(float4*)&Bs[bkr][bcq] = bv;
        __syncthreads();
#pragma unroll
        for (int kk = 0; kk < 16; ++kk) {
            float2 a2 = *(float2*)&As[kk][tr * 2];
            float4 b4 = *(float4*)&Bs[kk][tc * 4];
            acc[0][0] = fmaf(a2.x, b4.x, acc[0][0]);
            acc[0][1] = fmaf(a2.x, b4.y, acc[0][1]);
            acc[0][2] = fmaf(a2.x, b4.z, acc[0][2]);
            acc[0][3] = fmaf(a2.x, b4.w, acc[0][3]);
            acc[1][0] = fmaf(a2.y, b4.x, acc[1][0]);
            acc[1][1] = fmaf(a2.y, b4.y, acc[1][1]);
            acc[1][2] = fmaf(a2.y, b4.z, acc[1][2]);
            acc[1][3] = fmaf(a2.y, b4.w, acc[1][3]);
        }
        __syncthreads();
    }
#pragma unroll
    for (int i = 0; i < 2; ++i) {
        int m = m0 + tr * 2 + i;
        float4 val = make_float4(acc[i][0], acc[i][1], acc[i][2], acc[i][3]);
        *(float4*)&out[(size_t)m * N + n0 + tc * 4] = val;
    }
}

// ---------------------------------------------------------------------------
extern "C" void kernel_launch(void* const* d_in, const int* in_sizes, int n_in,
                              void* d_out, int out_size, void* d_ws, size_t ws_size,
                              hipStream_t stream) {
    (void)in_sizes; (void)n_in; (void)out_size; (void)ws_size;
    const float* x = (const float*)d_in[0];
    const int* bias_matrix = (const int*)d_in[1];
    const float* w_attn = (const float*)d_in[2];
    const float* w_proj = (const float*)d_in[3];
    const float* w_edge_k = (const float*)d_in[4];
    const float* w_edge_v = (const float*)d_in[5];
    const float* edge_emb = (const float*)d_in[6];
    const float* attn_bias = (const float*)d_in[7];
    float* out = (float*)d_out;

    const size_t n_qkv = (size_t)Bdim * Hdim * Tdim * Edim;
    float* ws = (float*)d_ws;
    float* qT = ws;
    float* kT = qT + n_qkv;
    float* vT = kT + n_qkv;
    float* y = vT + n_qkv;
    float* ekt = y + (size_t)Bdim * Tdim * Cdim;
    float* evt = ekt + (size_t)NTYPES * Cdim;

    pre_kernel<<<400, 256, 0, stream>>>(x, w_attn, edge_emb, w_edge_k, w_edge_v,
                                        qT, kT, vT, ekt, evt);
    attn_kernel<<<dim3(64 * 16), 512, 0, stream>>>(qT, kT, vT, bias_matrix,
                                                   ekt, evt, attn_bias, y);
    proj_gemm_kernel<<<dim3(4, 32), 256, 0, stream>>>(y, w_proj, out);
}

// Round 6
// 126.419 us; speedup vs baseline: 1.1028x; 1.0207x over previous
//
#include <hip/hip_runtime.h>
#include <hip/hip_bf16.h>
#include <math.h>

// Problem constants
#define Bdim 2
#define Tdim 512
#define Cdim 256
#define Hdim 8
#define Edim 32
#define NTYPES 16
#define TI 8       // i-tile size

// ---------------------------------------------------------------------------
// Kernel 1: fused edge-tables + qkv GEMM.
// blocks 0..383: qkv GEMM (M=1024,K=256,N=768), 32x64 tile, scatter (B,H,T,E)
// blocks 384..399: ekt/evt = emb[t] @ w_edge_{k,v}
// ---------------------------------------------------------------------------
__global__ __launch_bounds__(256) void pre_kernel(
    const float* __restrict__ A, const float* __restrict__ Bw,
    const float* __restrict__ emb, const float* __restrict__ wk,
    const float* __restrict__ wv,
    float* __restrict__ qT, float* __restrict__ kT, float* __restrict__ vT,
    float* __restrict__ ekt, float* __restrict__ evt)
{
    __shared__ float smem[16 * 34 + 16 * 64];
    int tid = threadIdx.x;

    if (blockIdx.x >= 384) {
        // ---- edge tables ----
        int t = blockIdx.x - 384;
        float* se = smem;
        se[tid] = emb[t * Cdim + tid];
        __syncthreads();
        float a = 0.f, b = 0.f;
        for (int k = 0; k < Cdim; ++k) {
            float ev = se[k];
            a = fmaf(ev, wk[k * Cdim + tid], a);
            b = fmaf(ev, wv[k * Cdim + tid], b);
        }
        ekt[t * Cdim + tid] = a;
        evt[t * Cdim + tid] = b;
        return;
    }

    const int N = 3 * Cdim;
    const int K = Cdim;
    float (*As)[34] = (float(*)[34])smem;
    float (*Bs)[64] = (float(*)[64])(smem + 16 * 34);
    int m0 = (blockIdx.x / 12) * 32;
    int n0 = (blockIdx.x % 12) * 64;
    int tr = tid >> 4, tc = tid & 15;
    float acc[2][4] = {};
    int bkr = tid >> 4, bcq = (tid & 15) * 4;

    for (int k0 = 0; k0 < K; k0 += 16) {
        if (tid < 128) {
            int r = tid >> 2, kq = (tid & 3) * 4;
            float4 av = *(const float4*)(A + (size_t)(m0 + r) * K + k0 + kq);
            As[kq + 0][r] = av.x;
            As[kq + 1][r] = av.y;
            As[kq + 2][r] = av.z;
            As[kq + 3][r] = av.w;
        }
        float4 bv = *(const float4*)(Bw + (size_t)(k0 + bkr) * N + n0 + bcq);
        *(float4*)&Bs[bkr][bcq] = bv;
        __syncthreads();
#pragma unroll
        for (int kk = 0; kk < 16; ++kk) {
            float2 a2 = *(float2*)&As[kk][tr * 2];
            float4 b4 = *(float4*)&Bs[kk][tc * 4];
            acc[0][0] = fmaf(a2.x, b4.x, acc[0][0]);
            acc[0][1] = fmaf(a2.x, b4.y, acc[0][1]);
            acc[0][2] = fmaf(a2.x, b4.z, acc[0][2]);
            acc[0][3] = fmaf(a2.x, b4.w, acc[0][3]);
            acc[1][0] = fmaf(a2.y, b4.x, acc[1][0]);
            acc[1][1] = fmaf(a2.y, b4.y, acc[1][1]);
            acc[1][2] = fmaf(a2.y, b4.z, acc[1][2]);
            acc[1][3] = fmaf(a2.y, b4.w, acc[1][3]);
        }
        __syncthreads();
    }
    int sec = n0 >> 8;
    float* dst = (sec == 0) ? qT : (sec == 1) ? kT : vT;
    int cc0 = (n0 & 255) + tc * 4;
    int h = cc0 >> 5;
    int e0 = cc0 & 31;
#pragma unroll
    for (int i = 0; i < 2; ++i) {
        int m = m0 + tr * 2 + i;
        int bq = m >> 9, t = m & (Tdim - 1);
        float4 val = make_float4(acc[i][0], acc[i][1], acc[i][2], acc[i][3]);
        *(float4*)&dst[(((size_t)bq * Hdim + h) * Tdim + t) * Edim + e0] = val;
    }
}

// Quad (4-lane) butterfly sum via DPP quad_perm — pure VALU, no LDS pipe.
__device__ __forceinline__ float quad_reduce_add(float s) {
    int t = __builtin_amdgcn_update_dpp(0, __float_as_int(s), 0xB1, 0xF, 0xF, true); // xor1
    s += __int_as_float(t);
    t = __builtin_amdgcn_update_dpp(0, __float_as_int(s), 0x4E, 0xF, 0xF, true);     // xor2
    s += __int_as_float(t);
    return s;
}

// ---------------------------------------------------------------------------
// Kernel 2: attention. Round-16: EXPLICIT SOFTWARE PIPELINING.
// R15 post-mortem: coalesced global-direct pass A (4 lanes/j, DPP quad
// reduce) WON (total 129.0, attn ~36). But VGPR_Count=36 shows the compiler
// does NOT pipeline the barrier-free A/B loops — each strip/chunk's global
// load latency (~300-900cy) sits on the critical path; LDS pipe only ~40%
// busy, occupancy 48% vs 100% cap => latency-bound.
// This round: manual register prefetch rotation in pass A (k-pair + type
// word for strip jb+128 loaded while computing jb) and pass B (v4 + tp for
// chunk jc+1), plus pass B's FIRST chunk loads issued BEFORE softmax (T14
// issue-early/use-late: they hide under the exp chain and [bar3]).
// LDS unchanged (~36.6KB); VGPR expected ~60-72 (WATCH <=84: >84 drops to
// 2 blocks/CU; no min-waves cap so no forced spill possible).
// Do NOT: min-waves>4 (R12: forced 40-VGPR spill, 161MB scratch), per-lane-
// row global k (R14: VMEM scatter serialization, 46us), kv LDS staging (R13:
// pipe+barrier cost exceeds reuse; k/v are L1/L2-resident), kv dbuf (R11),
// online softmax (R7-R9), qm removal (R10: +3us VALU).
// ---------------------------------------------------------------------------
__global__ __launch_bounds__(512, 4) void attn_kernel(
    const float* __restrict__ qT, const float* __restrict__ kT,
    const float* __restrict__ vT, const int* __restrict__ bm,
    const float* __restrict__ ekt, const float* __restrict__ evt,
    const float* __restrict__ abt, float* __restrict__ y)
{
    __shared__ float qm[TI][NTYPES][32];         // q*ekt, XOR-swizzled (16K)
    __shared__ float ss[TI][516];                // scores -> probs (16.1K)
    __shared__ unsigned int st1pf[Tdim];         // nibbles of bm[b,j,i0+ii] (2K)
    __shared__ float sevt[NTYPES][36];           // (2.25K)
    __shared__ float sabt[NTYPES];
    __shared__ float sinv[TI];
    // total ~36.6 KB

    float* spart = (float*)ss;                   // overlay AFTER pass B done

    // global LPT order: heaviest tau (njt=4) blocks dispatch first
    const int tau = 63 - (blockIdx.x >> 4);
    const int bh = blockIdx.x & 15;
    const int h = bh & (Hdim - 1);
    const int b = bh >> 3;
    const int tid = threadIdx.x;
    const int wave = tid >> 6;
    const int lane = tid & 63;
    const float inv_scale = 0.17677669529663687f;  // 1/sqrt(32)

    const float* qbase = qT + (size_t)bh * Tdim * Edim;
    const float* kbase = kT + (size_t)bh * Tdim * Edim;
    const float* vbase = vT + (size_t)bh * Tdim * Edim;
    const int* bmb = bm + (size_t)b * Tdim * Tdim;

    const int i0 = tau * TI;
    const int imax = i0 + TI - 1;
    const int jmax = (((imax >> 7) + 1) << 7);

    if (tid < 128) {
        int t = tid >> 3, eq = tid & 7;
        *(float4*)&sevt[t][eq * 4] = *(const float4*)&evt[t * Cdim + h * Edim + eq * 4];
    }
    if (tid < NTYPES) sabt[tid] = abt[tid * Hdim + h];
    // stage nibble table st1pf[j]: bm[b, j, i0..i0+7]
    if (tid < jmax) {
        const int* rowp = bmb + (size_t)tid * Tdim + i0;
        int4 lo = *(const int4*)rowp;
        int4 hi = *(const int4*)(rowp + 4);
        st1pf[tid] =
            ((unsigned)(lo.x & 15)) | (((unsigned)(lo.y & 15)) << 4) |
            (((unsigned)(lo.z & 15)) << 8) | (((unsigned)(lo.w & 15)) << 12) |
            (((unsigned)(hi.x & 15)) << 16) | (((unsigned)(hi.y & 15)) << 20) |
            (((unsigned)(hi.z & 15)) << 24) | (((unsigned)(hi.w & 15)) << 28);
    }
    // build qm[ii][t] = q[i0+ii] * ekt[t] directly from global (L1 absorbs
    // the x16 q-row and x8 ekt-row redundancy); quad-XOR swizzle on (t&7)
    for (int idx = tid; idx < TI * NTYPES * 8; idx += 512) {
        int eq = idx & 7;
        int t = (idx >> 3) & (NTYPES - 1);
        int r = idx >> 7;
        float4 qv = *(const float4*)&qbase[(size_t)(i0 + r) * Edim + eq * 4];
        float4 ev = *(const float4*)&ekt[t * Cdim + h * Edim + eq * 4];
        float4 o;
        o.x = qv.x * ev.x; o.y = qv.y * ev.y;
        o.z = qv.z * ev.z; o.w = qv.w * ev.w;
        *(float4*)&qm[r][t][(eq << 2) ^ ((t & 7) << 2)] = o;
    }
    __syncthreads();   // [bar 1] qm + st1pf + sevt + sabt ready

    // ---- Pass A: scores. Coalesced global k + manual prefetch rotation -----
    {
        const int g = lane >> 2;     // j sub-index within wave's 16-row strip
        const int c = lane & 3;      // e-slice: elements c*8 .. c*8+7
        const int e0 = c << 3;
        int jb = wave << 4;
        if (jb <= imax) {
            const float* krow = kbase + ((size_t)(jb + g) << 5) + e0;
            float4 k0 = *(const float4*)(krow);
            float4 k1 = *(const float4*)(krow + 4);
            unsigned tp = st1pf[jb + g];
            for (;;) {
                const int jbn = jb + 128;
                const bool more = (jbn <= imax);   // wave-uniform
                float4 kn0, kn1;
                unsigned tpn;
                if (more) {                         // prefetch next strip
                    const float* krn = kbase + ((size_t)(jbn + g) << 5) + e0;
                    kn0 = *(const float4*)(krn);
                    kn1 = *(const float4*)(krn + 4);
                    tpn = st1pf[jbn + g];
                }
                const int j = jb + g;
                float my0 = 0.f, my1 = 0.f;
#pragma unroll
                for (int ii = 0; ii < 8; ++ii) {
                    int t1 = (tp >> (ii * 4)) & 15;
                    int o0 = e0 ^ ((t1 & 7) << 2);
                    float4 q0 = *(float4*)&qm[ii][t1][o0];
                    float4 q1 = *(float4*)&qm[ii][t1][o0 ^ 4];
                    float s = q0.x * k0.x;
                    s = fmaf(q0.y, k0.y, s);
                    s = fmaf(q0.z, k0.z, s);
                    s = fmaf(q0.w, k0.w, s);
                    s = fmaf(q1.x, k1.x, s);
                    s = fmaf(q1.y, k1.y, s);
                    s = fmaf(q1.z, k1.z, s);
                    s = fmaf(q1.w, k1.w, s);
                    s = quad_reduce_add(s);          // all 4 lanes hold full dot
                    if (ii < 4) my0 = (c == ii) ? s : my0;       // static select
                    else        my1 = (c == (ii - 4)) ? s : my1;
                }
                if (j <= i0 + c)     ss[c][j]     = my0 * inv_scale;
                if (j <= i0 + c + 4) ss[c + 4][j] = my1 * inv_scale;
                if (!more) break;
                k0 = kn0; k1 = kn1; tp = tpn; jb = jbn;
            }
        }
    }
    __syncthreads();   // [bar 2] all scores written

    // Pass-B chunk-0 loads issued EARLY (hide under softmax + [bar 3]).
    const int gid8 = tid >> 3;       // 64 groups of 8 (8 lanes share a j)
    const int eqg4 = (tid & 7) << 2;
    float4 v4c = *(const float4*)&vbase[((size_t)gid8 << 5) + eqg4];
    unsigned tpc = st1pf[gid8];

    // ------- softmax (bias added here from global bm; norm deferred) -------
    {
        int ii = wave;
        int i = i0 + ii;
        const int* brow = bmb + (size_t)i * Tdim;   // bm[b, i, :], coalesced
        float tb[8];
        float m = -1e30f;
#pragma unroll
        for (int c = 0; c < 8; ++c) {
            int j = (c << 6) + lane;                // always < Tdim: safe read
            float val = ss[ii][j] + sabt[brow[j] & 15];
            tb[c] = (j <= i) ? val : -1e30f;        // select AFTER add: no NaN
            m = fmaxf(m, tb[c]);
        }
        for (int off = 32; off; off >>= 1) m = fmaxf(m, __shfl_xor(m, off));
        float sum = 0.f;
#pragma unroll
        for (int c = 0; c < 8; ++c) {
            int j = (c << 6) + lane;
            float p = __expf(tb[c] - m);
            p = (j <= i) ? p : 0.f;                 // kill exp(0)=1 of idle lanes
            sum += p;
            if (j <= i) ss[ii][j] = p;
        }
        for (int off = 32; off; off >>= 1) sum += __shfl_xor(sum, off);
        if (lane == 0) sinv[ii] = 1.0f / sum;
    }
    __syncthreads();   // [bar 3] probs + sinv visible

    // ---- Pass B: PV. Global-direct v + manual prefetch rotation ------------
    float4 acc[TI];
#pragma unroll
    for (int ii = 0; ii < TI; ++ii) acc[ii] = make_float4(0.f, 0.f, 0.f, 0.f);
    for (int jc = 0;; ++jc) {
        const bool more = ((jc + 1) << 6) <= imax;   // block-uniform
        float4 v4n;
        unsigned tpn;
        if (more) {                                   // prefetch next chunk
            const int jn = ((jc + 1) << 6) + gid8;
            v4n = *(const float4*)&vbase[((size_t)jn << 5) + eqg4];
            tpn = st1pf[jn];
        }
        const int j = (jc << 6) + gid8;
#pragma unroll
        for (int ii = 0; ii < TI; ++ii) {
            const int i = i0 + ii;
            if ((jc << 6) > i) continue;        // block-uniform skip
            float p = (j <= i) ? ss[ii][j] : 0.f;
            int t1 = (tpc >> (ii * 4)) & 15;
            float4 ev = *(float4*)&sevt[t1][eqg4];
            acc[ii].x = fmaf(p * ev.x, v4c.x, acc[ii].x);
            acc[ii].y = fmaf(p * ev.y, v4c.y, acc[ii].y);
            acc[ii].z = fmaf(p * ev.z, v4c.z, acc[ii].z);
            acc[ii].w = fmaf(p * ev.w, v4c.w, acc[ii].w);
        }
        if (!more) break;
        v4c = v4n; tpc = tpn;
    }
    __syncthreads();   // [bar 4] all ss reads done -> spart may overlay
    // reduce across the wave's 8 groups (lane bits 3,4,5)
#pragma unroll
    for (int ii = 0; ii < TI; ++ii) {
#pragma unroll
        for (int m = 8; m <= 32; m <<= 1) {
            acc[ii].x += __shfl_xor(acc[ii].x, m);
            acc[ii].y += __shfl_xor(acc[ii].y, m);
            acc[ii].z += __shfl_xor(acc[ii].z, m);
            acc[ii].w += __shfl_xor(acc[ii].w, m);
        }
    }
    if (lane < 8) {
#pragma unroll
        for (int ii = 0; ii < TI; ++ii)
            *(float4*)&spart[((wave * TI + ii) << 5) + lane * 4] = acc[ii];
    }
    __syncthreads();   // [bar 5]
    if (tid < TI * Edim) {
        int ii = tid >> 5, e = tid & 31;
        float yv = 0.f;
#pragma unroll
        for (int w = 0; w < 8; ++w) yv += spart[((w * TI + ii) << 5) + e];
        yv *= sinv[ii];
        y[((size_t)(b * Tdim + i0 + ii)) * Cdim + h * Edim + e] = yv;
    }
}

// ---------------------------------------------------------------------------
// Kernel 3: proj GEMM (M=1024, K=256, N=256) -> d_out (B,T,C).
// Round-16: 32x32 tiles, 256 blocks (was 128 -> half the GPU idle).
// ---------------------------------------------------------------------------
__global__ __launch_bounds__(256) void proj_gemm_kernel(
    const float* __restrict__ A, const float* __restrict__ Bw,
    float* __restrict__ out)
{
    const int N = Cdim;
    const int K = Cdim;
    __shared__ float As[16][34];
    __shared__ float Bs[16][36];
    int m0 = blockIdx.y * 32;
    int n0 = blockIdx.x * 32;
    int tid = threadIdx.x;
    int tr = tid >> 3;          // 0..31 (row)
    int tc = tid & 7;           // 0..7  (col quad)
    float acc[4] = {};

    for (int k0 = 0; k0 < K; k0 += 16) {
        if (tid < 128) {
            int r = tid >> 2, kq = (tid & 3) * 4;
            float4 av = *(const float4*)(A + (size_t)(m0 + r) * K + k0 + kq);
            As[kq + 0][r] = av.x;
            As[kq + 1][r] = av.y;
            As[kq + 2][r] = av.z;
            As[kq + 3][r] = av.w;
        } else {
            int t2 = tid - 128;
            int r = t2 >> 3, c = (t2 & 7) * 4;   // 16 rows x 32 cols
            *(float4*)&Bs[r][c] =
                *(const float4*)(Bw + (size_t)(k0 + r) * N + n0 + c);
        }
        __syncthreads();
#pragma unroll
        for (int kk = 0; kk < 16; ++kk) {
            float a = As[kk][tr];
            float4 b4 = *(float4*)&Bs[kk][tc * 4];
            acc[0] = fmaf(a, b4.x, acc[0]);
            acc[1] = fmaf(a, b4.y, acc[1]);
            acc[2] = fmaf(a, b4.z, acc[2]);
            acc[3] = fmaf(a, b4.w, acc[3]);
        }
        __syncthreads();
    }
    float4 val = make_float4(acc[0], acc[1], acc[2], acc[3]);
    *(float4*)&out[(size_t)(m0 + tr) * N + n0 + tc * 4] = val;
}

// ---------------------------------------------------------------------------
extern "C" void kernel_launch(void* const* d_in, const int* in_sizes, int n_in,
                              void* d_out, int out_size, void* d_ws, size_t ws_size,
                              hipStream_t stream) {
    (void)in_sizes; (void)n_in; (void)out_size; (void)ws_size;
    const float* x = (const float*)d_in[0];
    const int* bias_matrix = (const int*)d_in[1];
    const float* w_attn = (const float*)d_in[2];
    const float* w_proj = (const float*)d_in[3];
    const float* w_edge_k = (const float*)d_in[4];
    const float* w_edge_v = (const float*)d_in[5];
    const float* edge_emb = (const float*)d_in[6];
    const float* attn_bias = (const float*)d_in[7];
    float* out = (float*)d_out;

    const size_t n_qkv = (size_t)Bdim * Hdim * Tdim * Edim;
    float* ws = (float*)d_ws;
    float* qT = ws;
    float* kT = qT + n_qkv;
    float* vT = kT + n_qkv;
    float* y = vT + n_qkv;
    float* ekt = y + (size_t)Bdim * Tdim * Cdim;
    float* evt = ekt + (size_t)NTYPES * Cdim;

    pre_kernel<<<400, 256, 0, stream>>>(x, w_attn, edge_emb, w_edge_k, w_edge_v,
                                        qT, kT, vT, ekt, evt);
    attn_kernel<<<dim3(64 * 16), 512, 0, stream>>>(qT, kT, vT, bias_matrix,
                                                   ekt, evt, attn_bias, y);
    proj_gemm_kernel<<<dim3(8, 32), 256, 0, stream>>>(y, w_proj, out);
}

// Round 7
// 121.297 us; speedup vs baseline: 1.1493x; 1.0422x over previous
//
#include <hip/hip_runtime.h>
#include <hip/hip_bf16.h>
#include <hip/hip_fp16.h>
#include <math.h>

// Problem constants
#define Bdim 2
#define Tdim 512
#define Cdim 256
#define Hdim 8
#define Edim 32
#define NTYPES 16
#define TI 8       // i-tile size

// ---------------------------------------------------------------------------
// Kernel 1: fused edge-tables + qkv GEMM. Round-17: BK=32 (half the barriers).
// blocks 0..383: qkv GEMM (M=1024,K=256,N=768), 32x64 tile, scatter (B,H,T,E)
// blocks 384..399: ekt/evt = emb[t] @ w_edge_{k,v}
// ---------------------------------------------------------------------------
__global__ __launch_bounds__(256) void pre_kernel(
    const float* __restrict__ A, const float* __restrict__ Bw,
    const float* __restrict__ emb, const float* __restrict__ wk,
    const float* __restrict__ wv,
    float* __restrict__ qT, float* __restrict__ kT, float* __restrict__ vT,
    float* __restrict__ ekt, float* __restrict__ evt)
{
    __shared__ float smem[32 * 34 + 32 * 64];   // 12.5 KB
    int tid = threadIdx.x;

    if (blockIdx.x >= 384) {
        // ---- edge tables ----
        int t = blockIdx.x - 384;
        float* se = smem;
        se[tid] = emb[t * Cdim + tid];
        __syncthreads();
        float a = 0.f, b = 0.f;
        for (int k = 0; k < Cdim; ++k) {
            float ev = se[k];
            a = fmaf(ev, wk[k * Cdim + tid], a);
            b = fmaf(ev, wv[k * Cdim + tid], b);
        }
        ekt[t * Cdim + tid] = a;
        evt[t * Cdim + tid] = b;
        return;
    }

    const int N = 3 * Cdim;
    const int K = Cdim;
    float (*As)[34] = (float(*)[34])smem;            // [32][34] transposed A
    float (*Bs)[64] = (float(*)[64])(smem + 32 * 34);// [32][64]
    int m0 = (blockIdx.x / 12) * 32;
    int n0 = (blockIdx.x % 12) * 64;
    int tr = tid >> 4, tc = tid & 15;
    float acc[2][4] = {};

    for (int k0 = 0; k0 < K; k0 += 32) {
        {   // A tile: 32 rows x 32 k, one float4/thread, transposed store
            int r = tid >> 3, kq = (tid & 7) * 4;
            float4 av = *(const float4*)(A + (size_t)(m0 + r) * K + k0 + kq);
            As[kq + 0][r] = av.x;
            As[kq + 1][r] = av.y;
            As[kq + 2][r] = av.z;
            As[kq + 3][r] = av.w;
        }
        {   // B tile: 32 k-rows x 64 n, two float4/thread
            int br = tid >> 4, bc = (tid & 15) * 4;
            *(float4*)&Bs[br][bc] =
                *(const float4*)(Bw + (size_t)(k0 + br) * N + n0 + bc);
            *(float4*)&Bs[br + 16][bc] =
                *(const float4*)(Bw + (size_t)(k0 + br + 16) * N + n0 + bc);
        }
        __syncthreads();
#pragma unroll
        for (int kk = 0; kk < 32; ++kk) {
            float2 a2 = *(float2*)&As[kk][tr * 2];
            float4 b4 = *(float4*)&Bs[kk][tc * 4];
            acc[0][0] = fmaf(a2.x, b4.x, acc[0][0]);
            acc[0][1] = fmaf(a2.x, b4.y, acc[0][1]);
            acc[0][2] = fmaf(a2.x, b4.z, acc[0][2]);
            acc[0][3] = fmaf(a2.x, b4.w, acc[0][3]);
            acc[1][0] = fmaf(a2.y, b4.x, acc[1][0]);
            acc[1][1] = fmaf(a2.y, b4.y, acc[1][1]);
            acc[1][2] = fmaf(a2.y, b4.z, acc[1][2]);
            acc[1][3] = fmaf(a2.y, b4.w, acc[1][3]);
        }
        __syncthreads();
    }
    int sec = n0 >> 8;
    float* dst = (sec == 0) ? qT : (sec == 1) ? kT : vT;
    int cc0 = (n0 & 255) + tc * 4;
    int h = cc0 >> 5;
    int e0 = cc0 & 31;
#pragma unroll
    for (int i = 0; i < 2; ++i) {
        int m = m0 + tr * 2 + i;
        int bq = m >> 9, t = m & (Tdim - 1);
        float4 val = make_float4(acc[i][0], acc[i][1], acc[i][2], acc[i][3]);
        *(float4*)&dst[(((size_t)bq * Hdim + h) * Tdim + t) * Edim + e0] = val;
    }
}

// Quad (4-lane) butterfly sum via DPP quad_perm — pure VALU, no LDS pipe.
__device__ __forceinline__ float quad_reduce_add(float s) {
    int t = __builtin_amdgcn_update_dpp(0, __float_as_int(s), 0xB1, 0xF, 0xF, true); // xor1
    s += __int_as_float(t);
    t = __builtin_amdgcn_update_dpp(0, __float_as_int(s), 0x4E, 0xF, 0xF, true);     // xor2
    s += __int_as_float(t);
    return s;
}

// ---------------------------------------------------------------------------
// Kernel 2: attention. Round-17: FP16 qm + packed-fp16 dot.
// R16 analysis: attn ~33us, LDS pipe ~15-18us is the dominant per-CU serial
// resource; pass A's 2x ds_read_b128 per (ii) for the 32B fp32 qm slice is
// the single largest term. qm now stored fp16 [TI][NTYPES][40] (80B rows:
// 16B-aligned slices, 8 distinct bank starts) -> ONE b128 per (ii); dot via
// __hfma2 (k converted once/strip with cvt_pkrtz): 5 VALU/ii vs 8. Pass B
// (sevt/ss fp32) unchanged to keep the precision budget on one change.
// PRECISION GAMBLE: fp16 qm quantization + fp16 accumulation -> absmax est
// 1.5-3e-4 (from 6.1e-5). If this round FAILS verification, revert fp16.
// WATCH: VGPR<=64 keeps 4 blocks/CU (LDS 31.2KB).
// Do NOT: min-waves>4 (R12 spill), per-lane-row global k (R14 scatter), kv
// LDS staging (R13), kv dbuf (R11), online softmax (R7-R9), qm removal (R10).
// ---------------------------------------------------------------------------
__global__ __launch_bounds__(512, 4) void attn_kernel(
    const float* __restrict__ qT, const float* __restrict__ kT,
    const float* __restrict__ vT, const int* __restrict__ bm,
    const float* __restrict__ ekt, const float* __restrict__ evt,
    const float* __restrict__ abt, float* __restrict__ y)
{
    __shared__ __half qm[TI][NTYPES][40];        // q*ekt fp16, 80B rows (10.2K)
    __shared__ float ss[TI][516];                // scores -> probs (16.1K)
    __shared__ unsigned int st1pf[Tdim];         // nibbles of bm[b,j,i0+ii] (2K)
    __shared__ float sevt[NTYPES][36];           // (2.25K)
    __shared__ float sabt[NTYPES];
    __shared__ float sinv[TI];
    // total ~31.2 KB -> 4 blocks/CU at VGPR<=64

    float* spart = (float*)ss;                   // overlay AFTER pass B done

    // global LPT order: heaviest tau (njt=4) blocks dispatch first
    const int tau = 63 - (blockIdx.x >> 4);
    const int bh = blockIdx.x & 15;
    const int h = bh & (Hdim - 1);
    const int b = bh >> 3;
    const int tid = threadIdx.x;
    const int wave = tid >> 6;
    const int lane = tid & 63;
    const float inv_scale = 0.17677669529663687f;  // 1/sqrt(32)

    const float* qbase = qT + (size_t)bh * Tdim * Edim;
    const float* kbase = kT + (size_t)bh * Tdim * Edim;
    const float* vbase = vT + (size_t)bh * Tdim * Edim;
    const int* bmb = bm + (size_t)b * Tdim * Tdim;

    const int i0 = tau * TI;
    const int imax = i0 + TI - 1;
    const int jmax = (((imax >> 7) + 1) << 7);

    if (tid < 128) {
        int t = tid >> 3, eq = tid & 7;
        *(float4*)&sevt[t][eq * 4] = *(const float4*)&evt[t * Cdim + h * Edim + eq * 4];
    }
    if (tid < NTYPES) sabt[tid] = abt[tid * Hdim + h];
    // stage nibble table st1pf[j]: bm[b, j, i0..i0+7]
    if (tid < jmax) {
        const int* rowp = bmb + (size_t)tid * Tdim + i0;
        int4 lo = *(const int4*)rowp;
        int4 hi = *(const int4*)(rowp + 4);
        st1pf[tid] =
            ((unsigned)(lo.x & 15)) | (((unsigned)(lo.y & 15)) << 4) |
            (((unsigned)(lo.z & 15)) << 8) | (((unsigned)(lo.w & 15)) << 12) |
            (((unsigned)(hi.x & 15)) << 16) | (((unsigned)(hi.y & 15)) << 20) |
            (((unsigned)(hi.z & 15)) << 24) | (((unsigned)(hi.w & 15)) << 28);
    }
    // build qm[ii][t] = fp16(q[i0+ii] * ekt[t]) directly from global
    for (int idx = tid; idx < TI * NTYPES * 8; idx += 512) {
        int eq = idx & 7;
        int t = (idx >> 3) & (NTYPES - 1);
        int r = idx >> 7;
        float4 qv = *(const float4*)&qbase[(size_t)(i0 + r) * Edim + eq * 4];
        float4 ev = *(const float4*)&ekt[t * Cdim + h * Edim + eq * 4];
        union { __half2 h[2]; uint2 u; } pk;
        pk.h[0] = __floats2half2_rn(qv.x * ev.x, qv.y * ev.y);
        pk.h[1] = __floats2half2_rn(qv.z * ev.z, qv.w * ev.w);
        *(uint2*)&qm[r][t][eq * 4] = pk.u;   // 8B store, 8B-aligned
    }
    __syncthreads();   // [bar 1] qm + st1pf + sevt + sabt ready

    // ---- Pass A: coalesced global k + prefetch rotation + fp16 dot ---------
    {
        const int g = lane >> 2;     // j sub-index within wave's 16-row strip
        const int c = lane & 3;      // e-slice: elements c*8 .. c*8+7
        const int e0 = c << 3;
        int jb = wave << 4;
        if (jb <= imax) {
            const float* krow = kbase + ((size_t)(jb + g) << 5) + e0;
            float4 k0 = *(const float4*)(krow);
            float4 k1 = *(const float4*)(krow + 4);
            unsigned tp = st1pf[jb + g];
            for (;;) {
                const int jbn = jb + 128;
                const bool more = (jbn <= imax);   // wave-uniform
                float4 kn0, kn1;
                unsigned tpn;
                if (more) {                         // prefetch next strip
                    const float* krn = kbase + ((size_t)(jbn + g) << 5) + e0;
                    kn0 = *(const float4*)(krn);
                    kn1 = *(const float4*)(krn + 4);
                    tpn = st1pf[jbn + g];
                }
                const int j = jb + g;
                // convert k slice to packed fp16 once per strip
                __half2 kh0 = __floats2half2_rn(k0.x, k0.y);
                __half2 kh1 = __floats2half2_rn(k0.z, k0.w);
                __half2 kh2 = __floats2half2_rn(k1.x, k1.y);
                __half2 kh3 = __floats2half2_rn(k1.z, k1.w);
                float my0 = 0.f, my1 = 0.f;
#pragma unroll
                for (int ii = 0; ii < 8; ++ii) {
                    int t1 = (tp >> (ii * 4)) & 15;
                    uint4 qw = *(const uint4*)&qm[ii][t1][e0];  // 1x b128
                    __half2 q0 = *(__half2*)&qw.x;
                    __half2 q1 = *(__half2*)&qw.y;
                    __half2 q2 = *(__half2*)&qw.z;
                    __half2 q3 = *(__half2*)&qw.w;
                    __half2 sh = __hmul2(q0, kh0);
                    sh = __hfma2(q1, kh1, sh);
                    sh = __hfma2(q2, kh2, sh);
                    sh = __hfma2(q3, kh3, sh);
                    float s = __low2float(sh) + __high2float(sh);
                    s = quad_reduce_add(s);          // all 4 lanes hold full dot
                    if (ii < 4) my0 = (c == ii) ? s : my0;       // static select
                    else        my1 = (c == (ii - 4)) ? s : my1;
                }
                if (j <= i0 + c)     ss[c][j]     = my0 * inv_scale;
                if (j <= i0 + c + 4) ss[c + 4][j] = my1 * inv_scale;
                if (!more) break;
                k0 = kn0; k1 = kn1; tp = tpn; jb = jbn;
            }
        }
    }
    __syncthreads();   // [bar 2] all scores written

    // Pass-B chunk-0 loads issued EARLY (hide under softmax + [bar 3]).
    const int gid8 = tid >> 3;       // 64 groups of 8 (8 lanes share a j)
    const int eqg4 = (tid & 7) << 2;
    float4 v4c = *(const float4*)&vbase[((size_t)gid8 << 5) + eqg4];
    unsigned tpc = st1pf[gid8];

    // ------- softmax (bias added here from global bm; norm deferred) -------
    {
        int ii = wave;
        int i = i0 + ii;
        const int* brow = bmb + (size_t)i * Tdim;   // bm[b, i, :], coalesced
        float tb[8];
        float m = -1e30f;
#pragma unroll
        for (int c = 0; c < 8; ++c) {
            int j = (c << 6) + lane;                // always < Tdim: safe read
            float val = ss[ii][j] + sabt[brow[j] & 15];
            tb[c] = (j <= i) ? val : -1e30f;        // select AFTER add: no NaN
            m = fmaxf(m, tb[c]);
        }
        for (int off = 32; off; off >>= 1) m = fmaxf(m, __shfl_xor(m, off));
        float sum = 0.f;
#pragma unroll
        for (int c = 0; c < 8; ++c) {
            int j = (c << 6) + lane;
            float p = __expf(tb[c] - m);
            p = (j <= i) ? p : 0.f;                 // kill exp(0)=1 of idle lanes
            sum += p;
            if (j <= i) ss[ii][j] = p;
        }
        for (int off = 32; off; off >>= 1) sum += __shfl_xor(sum, off);
        if (lane == 0) sinv[ii] = 1.0f / sum;
    }
    __syncthreads();   // [bar 3] probs + sinv visible

    // ---- Pass B: PV. Global-direct v + manual prefetch rotation ------------
    float4 acc[TI];
#pragma unroll
    for (int ii = 0; ii < TI; ++ii) acc[ii] = make_float4(0.f, 0.f, 0.f, 0.f);
    for (int jc = 0;; ++jc) {
        const bool more = ((jc + 1) << 6) <= imax;   // block-uniform
        float4 v4n;
        unsigned tpn;
        if (more) {                                   // prefetch next chunk
            const int jn = ((jc + 1) << 6) + gid8;
            v4n = *(const float4*)&vbase[((size_t)jn << 5) + eqg4];
            tpn = st1pf[jn];
        }
        const int j = (jc << 6) + gid8;
#pragma unroll
        for (int ii = 0; ii < TI; ++ii) {
            const int i = i0 + ii;
            if ((jc << 6) > i) continue;        // block-uniform skip
            float p = (j <= i) ? ss[ii][j] : 0.f;
            int t1 = (tpc >> (ii * 4)) & 15;
            float4 ev = *(float4*)&sevt[t1][eqg4];
            acc[ii].x = fmaf(p * ev.x, v4c.x, acc[ii].x);
            acc[ii].y = fmaf(p * ev.y, v4c.y, acc[ii].y);
            acc[ii].z = fmaf(p * ev.z, v4c.z, acc[ii].z);
            acc[ii].w = fmaf(p * ev.w, v4c.w, acc[ii].w);
        }
        if (!more) break;
        v4c = v4n; tpc = tpn;
    }
    __syncthreads();   // [bar 4] all ss reads done -> spart may overlay
    // reduce across the wave's 8 groups (lane bits 3,4,5)
#pragma unroll
    for (int ii = 0; ii < TI; ++ii) {
#pragma unroll
        for (int m = 8; m <= 32; m <<= 1) {
            acc[ii].x += __shfl_xor(acc[ii].x, m);
            acc[ii].y += __shfl_xor(acc[ii].y, m);
            acc[ii].z += __shfl_xor(acc[ii].z, m);
            acc[ii].w += __shfl_xor(acc[ii].w, m);
        }
    }
    if (lane < 8) {
#pragma unroll
        for (int ii = 0; ii < TI; ++ii)
            *(float4*)&spart[((wave * TI + ii) << 5) + lane * 4] = acc[ii];
    }
    __syncthreads();   // [bar 5]
    if (tid < TI * Edim) {
        int ii = tid >> 5, e = tid & 31;
        float yv = 0.f;
#pragma unroll
        for (int w = 0; w < 8; ++w) yv += spart[((w * TI + ii) << 5) + e];
        yv *= sinv[ii];
        y[((size_t)(b * Tdim + i0 + ii)) * Cdim + h * Edim + e] = yv;
    }
}

// ---------------------------------------------------------------------------
// Kernel 3: proj GEMM (M=1024, K=256, N=256) -> d_out (B,T,C).
// 32x32 tiles, 256 blocks.
// ---------------------------------------------------------------------------
__global__ __launch_bounds__(256) void proj_gemm_kernel(
    const float* __restrict__ A, const float* __restrict__ Bw,
    float* __restrict__ out)
{
    const int N = Cdim;
    const int K = Cdim;
    __shared__ float As[16][34];
    __shared__ float Bs[16][36];
    int m0 = blockIdx.y * 32;
    int n0 = blockIdx.x * 32;
    int tid = threadIdx.x;
    int tr = tid >> 3;          // 0..31 (row)
    int tc = tid & 7;           // 0..7  (col quad)
    float acc[4] = {};

    for (int k0 = 0; k0 < K; k0 += 16) {
        if (tid < 128) {
            int r = tid >> 2, kq = (tid & 3) * 4;
            float4 av = *(const float4*)(A + (size_t)(m0 + r) * K + k0 + kq);
            As[kq + 0][r] = av.x;
            As[kq + 1][r] = av.y;
            As[kq + 2][r] = av.z;
            As[kq + 3][r] = av.w;
        } else {
            int t2 = tid - 128;
            int r = t2 >> 3, c = (t2 & 7) * 4;   // 16 rows x 32 cols
            *(float4*)&Bs[r][c] =
                *(const float4*)(Bw + (size_t)(k0 + r) * N + n0 + c);
        }
        __syncthreads();
#pragma unroll
        for (int kk = 0; kk < 16; ++kk) {
            float a = As[kk][tr];
            float4 b4 = *(float4*)&Bs[kk][tc * 4];
            acc[0] = fmaf(a, b4.x, acc[0]);
            acc[1] = fmaf(a, b4.y, acc[1]);
            acc[2] = fmaf(a, b4.z, acc[2]);
            acc[3] = fmaf(a, b4.w, acc[3]);
        }
        __syncthreads();
    }
    float4 val = make_float4(acc[0], acc[1], acc[2], acc[3]);
    *(float4*)&out[(size_t)(m0 + tr) * N + n0 + tc * 4] = val;
}

// ---------------------------------------------------------------------------
extern "C" void kernel_launch(void* const* d_in, const int* in_sizes, int n_in,
                              void* d_out, int out_size, void* d_ws, size_t ws_size,
                              hipStream_t stream) {
    (void)in_sizes; (void)n_in; (void)out_size; (void)ws_size;
    const float* x = (const float*)d_in[0];
    const int* bias_matrix = (const int*)d_in[1];
    const float* w_attn = (const float*)d_in[2];
    const float* w_proj = (const float*)d_in[3];
    const float* w_edge_k = (const float*)d_in[4];
    const float* w_edge_v = (const float*)d_in[5];
    const float* edge_emb = (const float*)d_in[6];
    const float* attn_bias = (const float*)d_in[7];
    float* out = (float*)d_out;

    const size_t n_qkv = (size_t)Bdim * Hdim * Tdim * Edim;
    float* ws = (float*)d_ws;
    float* qT = ws;
    float* kT = qT + n_qkv;
    float* vT = kT + n_qkv;
    float* y = vT + n_qkv;
    float* ekt = y + (size_t)Bdim * Tdim * Cdim;
    float* evt = ekt + (size_t)NTYPES * Cdim;

    pre_kernel<<<400, 256, 0, stream>>>(x, w_attn, edge_emb, w_edge_k, w_edge_v,
                                        qT, kT, vT, ekt, evt);
    attn_kernel<<<dim3(64 * 16), 512, 0, stream>>>(qT, kT, vT, bias_matrix,
                                                   ekt, evt, attn_bias, y);
    proj_gemm_kernel<<<dim3(8, 32), 256, 0, stream>>>(y, w_proj, out);
}